// Round 1
// baseline (121.226 us; speedup 1.0000x reference)
//
#include <hip/hip_runtime.h>
#include <hip/hip_bf16.h>

#define NEMIT 512
#define ZPLANES 8
#define ROISIZE 20
#define SPL_D 64
#define SPL_H 40
#define SPL_W 40
#define NPIX (ROISIZE * ROISIZE)   // 400

// One block per (emitter, plane). 256 threads; each thread owns pixels tid and tid+256.
__global__ __launch_bounds__(256)
void psf_kernel(const float* __restrict__ pos,
                const float* __restrict__ inten,
                const float* __restrict__ bg,
                const float* __restrict__ coefs,
                float* __restrict__ out) {
    const int blk = blockIdx.x;          // n*ZPLANES + z
    const int n = blk >> 3;
    const int z = blk & 7;
    const int tid = threadIdx.x;

    const float p0 = pos[n * 3 + 0];     // indexes y (faithful to reference)
    const float p1 = pos[n * 3 + 1];     // indexes x
    const float p2 = pos[n * 3 + 2];     // indexes z

    // z-coordinate: same for the whole block
    const float pzc = (float)z - p2 + (float)(SPL_D / 2 - ZPLANES / 2);  // +28
    const float fz = floorf(pzc);
    const float dz = pzc - fz;
    int iz = (int)fz;
    iz = min(max(iz, 0), SPL_D - 1);
    float pzp[4];
    pzp[0] = 1.0f; pzp[1] = dz; pzp[2] = dz * dz; pzp[3] = dz * dz * dz;

    float vals[2];
    float lsum = 0.0f;

#pragma unroll
    for (int k = 0; k < 2; ++k) {
        const int p = tid + k * 256;
        float v = 0.0f;
        if (p < NPIX) {
            const int y = p / ROISIZE;
            const int x = p - y * ROISIZE;
            const float pyc = (float)y - p0 + (float)(SPL_H / 2 - ROISIZE / 2);  // +10
            const float pxc = (float)x - p1 + (float)(SPL_W / 2 - ROISIZE / 2);  // +10
            const float fy = floorf(pyc);
            const float fx = floorf(pxc);
            const float dy = pyc - fy;
            const float dx = pxc - fx;
            int iy = (int)fy; iy = min(max(iy, 0), SPL_H - 1);
            int ix = (int)fx; ix = min(max(ix, 0), SPL_W - 1);

            const float4* __restrict__ c =
                (const float4*)(coefs + (((size_t)iz * SPL_H + iy) * SPL_W + ix) * 64);

            float pyp[4];
            pyp[0] = 1.0f; pyp[1] = dy; pyp[2] = dy * dy; pyp[3] = dy * dy * dy;
            const float dx1 = dx, dx2 = dx * dx, dx3 = dx * dx * dx;

            float acc = 0.0f;
#pragma unroll
            for (int ez = 0; ez < 4; ++ez) {
                float az = 0.0f;
#pragma unroll
                for (int ey = 0; ey < 4; ++ey) {
                    const float4 cv = c[ez * 4 + ey];
                    float s = cv.x;
                    s = fmaf(cv.y, dx1, s);
                    s = fmaf(cv.z, dx2, s);
                    s = fmaf(cv.w, dx3, s);
                    az = fmaf(pyp[ey], s, az);
                }
                acc = fmaf(pzp[ez], az, acc);
            }
            v = acc;
        }
        vals[k] = v;
        lsum += v;
    }

    // Block reduction: wave64 shuffle then LDS combine of 4 waves.
#pragma unroll
    for (int off = 32; off > 0; off >>= 1)
        lsum += __shfl_down(lsum, off);

    __shared__ float wsum[4];
    const int wid = tid >> 6;
    const int lane = tid & 63;
    if (lane == 0) wsum[wid] = lsum;
    __syncthreads();
    const float total = wsum[0] + wsum[1] + wsum[2] + wsum[3];

    const float I = inten[n * ZPLANES + z];
    const float B = bg[n * ZPLANES + z];
    const float scale = I / total;

    float* __restrict__ o = out + ((size_t)n * ZPLANES + z) * NPIX;
#pragma unroll
    for (int k = 0; k < 2; ++k) {
        const int p = tid + k * 256;
        if (p < NPIX) o[p] = fmaf(vals[k], scale, B);
    }
}

extern "C" void kernel_launch(void* const* d_in, const int* in_sizes, int n_in,
                              void* d_out, int out_size, void* d_ws, size_t ws_size,
                              hipStream_t stream) {
    const float* pos   = (const float*)d_in[0];   // [512, 3]
    const float* inten = (const float*)d_in[1];   // [512, 8]
    const float* bg    = (const float*)d_in[2];   // [512, 8]
    const float* coefs = (const float*)d_in[3];   // [64, 40, 40, 64]
    float* out = (float*)d_out;                   // [512, 8, 20, 20]

    const int nblocks = NEMIT * ZPLANES;          // 4096
    psf_kernel<<<nblocks, 256, 0, stream>>>(pos, inten, bg, coefs, out);
}

// Round 8
// 92.333 us; speedup vs baseline: 1.3129x; 1.3129x over previous
//
#include <hip/hip_runtime.h>
#include <hip/hip_bf16.h>

#define NEMIT 512
#define ZPLANES 8
#define ROISIZE 20
#define SPL_D 64
#define SPL_H 40
#define SPL_W 40
#define NPIX (ROISIZE * ROISIZE)   // 400

// One block per (emitter, plane). 256 threads.
// Key facts exploited:
//  - (dz,dy,dx) and the cell-base offsets are uniform across the block
//    (pixel coords are integers, so frac(k - p + C) is k-independent).
//  - each output pixel uses exactly one cell of 64 contiguous floats (256 B).
// Layout: 8 lanes per cell. Lane sub s reads float4 #s and #(s+8) of the cell
// -> each load instruction is 8 x 128B fully-dense line segments (coalesced).
// Weighted partial uses two hoisted scalars; 3x shfl_xor reduces the group.
__global__ __launch_bounds__(256)
void psf_kernel(const float* __restrict__ pos,
                const float* __restrict__ inten,
                const float* __restrict__ bg,
                const float* __restrict__ coefs,
                float* __restrict__ out) {
    const int blk = blockIdx.x;          // n*ZPLANES + z
    const int n = blk >> 3;
    const int z = blk & 7;
    const int tid = threadIdx.x;

    const float p0 = pos[n * 3 + 0];     // indexes y (faithful to reference)
    const float p1 = pos[n * 3 + 1];     // indexes x
    const float p2 = pos[n * 3 + 2];     // indexes z

    // Uniform fractional parts + integer base offsets.
    // pzc = z - p2 + 28 ; iz = floor(pzc) (block-uniform), dz = frac.
    const float azf = (float)z - p2 + 28.0f;
    const float fzf = floorf(azf);
    const float dz = azf - fzf;
    int iz = (int)fzf;
    iz = min(max(iz, 0), SPL_D - 1);

    // pyc = y - p0 + 10 ; iy = y + floor(10-p0), dy = frac(10-p0).
    const float ayf = 10.0f - p0;
    const float fyf = floorf(ayf);
    const float dy = ayf - fyf;
    const int cy = (int)fyf;

    const float axf = 10.0f - p1;
    const float fxf = floorf(axf);
    const float dx = axf - fxf;
    const int cx = (int)fxf;

    // Power bases (uniform).
    const float dz2 = dz * dz, dz3 = dz2 * dz;
    const float dy2 = dy * dy, dy3 = dy2 * dy;
    const float dx2 = dx * dx, dx3 = dx2 * dx;
    const float pz[4] = {1.0f, dz, dz2, dz3};
    const float py[4] = {1.0f, dy, dy2, dy3};

    // Per-lane hoisted weights: lane sub s covers (ez = s>>2, ey = s&3) for
    // float4 #s (k=0) and (ez = 2+(s>>2), ey = s&3) for float4 #(s+8) (k=1).
    const int sub = tid & 7;
    const float pyw = py[sub & 3];
    const float w0 = pz[sub >> 2] * pyw;
    const float w1 = pz[2 + (sub >> 2)] * pyw;

    __shared__ float vals[NPIX];

    const int group = tid >> 3;          // 32 cell-groups per pass
#pragma unroll 2
    for (int pass = 0; pass < 13; ++pass) {
        const int c = pass * 32 + group; // cell == pixel index
        float v = 0.0f;
        if (c < NPIX) {
            const int y = c / ROISIZE;
            const int x = c - y * ROISIZE;
            int iy = y + cy; iy = min(max(iy, 0), SPL_H - 1);
            int ix = x + cx; ix = min(max(ix, 0), SPL_W - 1);
            const float4* __restrict__ cp =
                (const float4*)(coefs + (((size_t)iz * SPL_H + iy) * SPL_W + ix) * 64) + sub;
            const float4 A0 = cp[0];
            const float4 A1 = cp[8];
            float d0 = A0.x;
            d0 = fmaf(A0.y, dx, d0);
            d0 = fmaf(A0.z, dx2, d0);
            d0 = fmaf(A0.w, dx3, d0);
            float d1 = A1.x;
            d1 = fmaf(A1.y, dx, d1);
            d1 = fmaf(A1.z, dx2, d1);
            d1 = fmaf(A1.w, dx3, d1);
            v = fmaf(w1, d1, w0 * d0);
        }
        // Reduce the 8-lane group.
        v += __shfl_xor(v, 1);
        v += __shfl_xor(v, 2);
        v += __shfl_xor(v, 4);
        if (c < NPIX && sub == 0) vals[c] = v;
    }
    __syncthreads();

    // Block sum of 400 values.
    float lsum = vals[tid];
    if (tid < NPIX - 256) lsum += vals[tid + 256];
#pragma unroll
    for (int off = 32; off > 0; off >>= 1)
        lsum += __shfl_down(lsum, off);

    __shared__ float wsum[4];
    const int wid = tid >> 6;
    const int lane = tid & 63;
    if (lane == 0) wsum[wid] = lsum;
    __syncthreads();
    const float total = wsum[0] + wsum[1] + wsum[2] + wsum[3];

    const float I = inten[n * ZPLANES + z];
    const float B = bg[n * ZPLANES + z];
    const float scale = I / total;

    float* __restrict__ o = out + (size_t)blk * NPIX;
    o[tid] = fmaf(vals[tid], scale, B);
    if (tid < NPIX - 256) o[tid + 256] = fmaf(vals[tid + 256], scale, B);
}

extern "C" void kernel_launch(void* const* d_in, const int* in_sizes, int n_in,
                              void* d_out, int out_size, void* d_ws, size_t ws_size,
                              hipStream_t stream) {
    const float* pos   = (const float*)d_in[0];   // [512, 3]
    const float* inten = (const float*)d_in[1];   // [512, 8]
    const float* bg    = (const float*)d_in[2];   // [512, 8]
    const float* coefs = (const float*)d_in[3];   // [64, 40, 40, 64]
    float* out = (float*)d_out;                   // [512, 8, 20, 20]

    const int nblocks = NEMIT * ZPLANES;          // 4096
    psf_kernel<<<nblocks, 256, 0, stream>>>(pos, inten, bg, coefs, out);
}

// Round 10
// 85.868 us; speedup vs baseline: 1.4118x; 1.0753x over previous
//
#include <hip/hip_runtime.h>
#include <hip/hip_bf16.h>

#define NEMIT 512
#define ZPLANES 8
#define ROISIZE 20
#define SPL_D 64
#define SPL_H 40
#define SPL_W 40
#define NPIX (ROISIZE * ROISIZE)   // 400
#define E 16                        // emitters per block
#define NGROUPS (NEMIT / E)         // 32
#define HALF_CELLS 200
#define HALF_CHUNKS (HALF_CELLS * 16)  // 3200 float4 chunks per half-slab

// Block = (z, group of 16 emitters), 512 threads, thread owns one cell (pixel).
// Generic facts: for pos in [0,1), iz = z+27, cy = cx = 9, dz = 1-p2 etc. are
// per-emitter constants; all emitters in a z-plane read the SAME 20x20 cell
// window. Thread caches its cell's 64 coefs in 16 float4 regs (staged via LDS,
// XOR-swizzled chunks: lds_chunk = g ^ ((g>>4)&15) -> coalesced global loads
// AND ~2-way ds_read_b128). Then 16-emitter loop: 64 FMA each, basis scalars
// broadcast from LDS. Per-emitter mismatch (p==0.0 exactly) falls back to a
// direct global gather — correct for any input, ~never taken.
__global__ __launch_bounds__(512)
void psf_kernel(const float* __restrict__ pos,
                const float* __restrict__ inten,
                const float* __restrict__ bg,
                const float* __restrict__ coefs,
                float* __restrict__ out) {
    const int group = blockIdx.x >> 3;   // 32 groups
    const int z = blockIdx.x & 7;        // consecutive blocks differ in z ->
                                         // same-z blocks land on one XCD (L2 share)
    const int tid = threadIdx.x;
    const int cell = tid;                // pixel index y*20+x, valid if < 400

    __shared__ float4 slab4[HALF_CHUNKS];     // 51.2 KB, reused as vals later
    __shared__ float4 pw4[E][6];              // [0..3]=w quads, [4]=(dx,dx2,dx3,I), [5]=(B,-,-,-)
    __shared__ int4   pint4[E];               // (iz, cy, cx, match)
    __shared__ float  sscale[E], sbg[E];

    // ---- phase 0: per-emitter params (threads 0..15) ----
    if (tid < E) {
        const int n = group * E + tid;
        const float p0 = pos[n * 3 + 0];
        const float p1 = pos[n * 3 + 1];
        const float p2 = pos[n * 3 + 2];
        const float azf = (float)z - p2 + 28.0f;
        const float fzf = floorf(azf);
        const float dz = azf - fzf;
        int iz = (int)fzf; iz = min(max(iz, 0), SPL_D - 1);
        const float ayf = 10.0f - p0;
        const float fyf = floorf(ayf);
        const float dy = ayf - fyf;
        const int cy = (int)fyf;
        const float axf = 10.0f - p1;
        const float fxf = floorf(axf);
        const float dx = axf - fxf;
        const int cx = (int)fxf;
        const float pz[4] = {1.0f, dz, dz * dz, dz * dz * dz};
        const float py[4] = {1.0f, dy, dy * dy, dy * dy * dy};
        pw4[tid][0] = make_float4(pz[0]*py[0], pz[0]*py[1], pz[0]*py[2], pz[0]*py[3]);
        pw4[tid][1] = make_float4(pz[1]*py[0], pz[1]*py[1], pz[1]*py[2], pz[1]*py[3]);
        pw4[tid][2] = make_float4(pz[2]*py[0], pz[2]*py[1], pz[2]*py[2], pz[2]*py[3]);
        pw4[tid][3] = make_float4(pz[3]*py[0], pz[3]*py[1], pz[3]*py[2], pz[3]*py[3]);
        pw4[tid][4] = make_float4(dx, dx * dx, dx * dx * dx, inten[n * ZPLANES + z]);
        pw4[tid][5] = make_float4(bg[n * ZPLANES + z], 0.f, 0.f, 0.f);
        const int match = (iz == z + 27) && (cy == 9) && (cx == 9);
        pint4[tid] = make_int4(iz, cy, cx, match);
    }

    // Slab base: cell (y,x) -> coefs[z+27][9+y][9+x][0..63]
    const float* slabBase = coefs + (((size_t)(z + 27) * SPL_H + 9) * SPL_W + 9) * 64;

    // ---- stage half A: rows 0..9 (cells 0..199) ----
    for (int g = tid; g < HALF_CHUNKS; g += 512) {
        const int row = g / 320;             // 320 chunks per row (20 cells * 16)
        const int rem = g - row * 320;
        slab4[g ^ ((g >> 4) & 15)] = ((const float4*)(slabBase + row * (SPL_W * 64)))[rem];
    }
    __syncthreads();

    float4 r[16];
    if (cell < HALF_CELLS) {
#pragma unroll
        for (int k = 0; k < 16; ++k)
            r[k] = slab4[cell * 16 + (k ^ (cell & 15))];
    }
    __syncthreads();   // half-A reads done before overwrite

    // ---- stage half B: rows 10..19 (cells 200..399) ----
    for (int g = tid; g < HALF_CHUNKS; g += 512) {
        const int row = g / 320;
        const int rem = g - row * 320;
        slab4[g ^ ((g >> 4) & 15)] = ((const float4*)(slabBase + (10 + row) * (SPL_W * 64)))[rem];
    }
    __syncthreads();

    if (cell >= HALF_CELLS && cell < NPIX) {
        const int L = cell - HALF_CELLS;
#pragma unroll
        for (int k = 0; k < 16; ++k)
            r[k] = slab4[L * 16 + (k ^ (L & 15))];
    }
    __syncthreads();   // half-B reads done before vals overwrite

    // ---- phase 2: emitter loop, vals into LDS (aliases slab4) ----
    float* vals = reinterpret_cast<float*>(slab4);   // 16*400*4 = 25.6 KB <= 51.2 KB
    for (int e = 0; e < E; ++e) {
        const float4 wA = pw4[e][0], wB = pw4[e][1], wC = pw4[e][2], wD = pw4[e][3];
        const float4 dxv = pw4[e][4];
        const int4 pe = pint4[e];
        if (cell < NPIX) {
            float wq[16] = {wA.x, wA.y, wA.z, wA.w, wB.x, wB.y, wB.z, wB.w,
                            wC.x, wC.y, wC.z, wC.w, wD.x, wD.y, wD.z, wD.w};
            float v = 0.0f;
            if (pe.w) {
#pragma unroll
                for (int q = 0; q < 16; ++q) {
                    const float4 rq = r[q];
                    const float sx = fmaf(rq.w, dxv.z, fmaf(rq.z, dxv.y, fmaf(rq.y, dxv.x, rq.x)));
                    v = fmaf(wq[q], sx, v);
                }
            } else {
                // exact fallback (p component == 0.0 etc.): direct global gather
                const int y = cell / ROISIZE;
                const int x = cell - y * ROISIZE;
                int iy = y + pe.y; iy = min(max(iy, 0), SPL_H - 1);
                int ix = x + pe.z; ix = min(max(ix, 0), SPL_W - 1);
                const float4* cp = (const float4*)(coefs + (((size_t)pe.x * SPL_H + iy) * SPL_W + ix) * 64);
#pragma unroll
                for (int q = 0; q < 16; ++q) {
                    const float4 rq = cp[q];
                    const float sx = fmaf(rq.w, dxv.z, fmaf(rq.z, dxv.y, fmaf(rq.y, dxv.x, rq.x)));
                    v = fmaf(wq[q], sx, v);
                }
            }
            vals[e * NPIX + cell] = v;
        }
    }
    __syncthreads();

    // ---- phase 3: per-emitter totals (8 waves x 2 emitters) ----
    const int wid = tid >> 6;
    const int lane = tid & 63;
    for (int e = wid * 2; e < wid * 2 + 2; ++e) {
        float s = 0.0f;
        for (int c = lane; c < NPIX; c += 64) s += vals[e * NPIX + c];
#pragma unroll
        for (int off = 32; off > 0; off >>= 1) s += __shfl_down(s, off);
        if (lane == 0) {
            sscale[e] = pw4[e][4].w / s;   // I / total
            sbg[e] = pw4[e][5].x;
        }
    }
    __syncthreads();

    // ---- phase 4: scale + background + store ----
    if (cell < NPIX) {
        for (int e = 0; e < E; ++e) {
            const size_t n = (size_t)(group * E + e);
            out[(n * ZPLANES + z) * NPIX + cell] = fmaf(vals[e * NPIX + cell], sscale[e], sbg[e]);
        }
    }
}

extern "C" void kernel_launch(void* const* d_in, const int* in_sizes, int n_in,
                              void* d_out, int out_size, void* d_ws, size_t ws_size,
                              hipStream_t stream) {
    const float* pos   = (const float*)d_in[0];   // [512, 3]
    const float* inten = (const float*)d_in[1];   // [512, 8]
    const float* bg    = (const float*)d_in[2];   // [512, 8]
    const float* coefs = (const float*)d_in[3];   // [64, 40, 40, 64]
    float* out = (float*)d_out;                   // [512, 8, 20, 20]

    psf_kernel<<<ZPLANES * NGROUPS, 512, 0, stream>>>(pos, inten, bg, coefs, out);
}

// Round 11
// 85.120 us; speedup vs baseline: 1.4242x; 1.0088x over previous
//
#include <hip/hip_runtime.h>
#include <hip/hip_bf16.h>

#define NEMIT 512
#define ZPLANES 8
#define ROISIZE 20
#define SPL_D 64
#define SPL_H 40
#define SPL_W 40
#define NPIX (ROISIZE * ROISIZE)   // 400
#define E 8                         // emitters per block (A/B vs round-10's 16)
#define NGROUPS (NEMIT / E)         // 64
#define HALF_CELLS 200
#define HALF_CHUNKS (HALF_CELLS * 16)  // 3200 float4 chunks per half-slab

// Block = (z, group of E emitters), 512 threads, thread owns one cell (pixel).
// Same structure as round-10 (E=16) except E=8 -> 512 blocks (2/CU capacity),
// halved per-thread serial work, tail-imbalance robust. Single-variable A/B.
__global__ __launch_bounds__(512)
void psf_kernel(const float* __restrict__ pos,
                const float* __restrict__ inten,
                const float* __restrict__ bg,
                const float* __restrict__ coefs,
                float* __restrict__ out) {
    const int group = blockIdx.x >> 3;   // 64 groups
    const int z = blockIdx.x & 7;
    const int tid = threadIdx.x;
    const int cell = tid;                // pixel index y*20+x, valid if < 400

    __shared__ float4 slab4[HALF_CHUNKS];     // 51.2 KB, reused as vals later
    __shared__ float4 pw4[E][6];              // [0..3]=w quads, [4]=(dx,dx2,dx3,I), [5]=(B,-,-,-)
    __shared__ int4   pint4[E];               // (iz, cy, cx, match)
    __shared__ float  sscale[E], sbg[E];

    // ---- phase 0: per-emitter params (threads 0..E-1) ----
    if (tid < E) {
        const int n = group * E + tid;
        const float p0 = pos[n * 3 + 0];
        const float p1 = pos[n * 3 + 1];
        const float p2 = pos[n * 3 + 2];
        const float azf = (float)z - p2 + 28.0f;
        const float fzf = floorf(azf);
        const float dz = azf - fzf;
        int iz = (int)fzf; iz = min(max(iz, 0), SPL_D - 1);
        const float ayf = 10.0f - p0;
        const float fyf = floorf(ayf);
        const float dy = ayf - fyf;
        const int cy = (int)fyf;
        const float axf = 10.0f - p1;
        const float fxf = floorf(axf);
        const float dx = axf - fxf;
        const int cx = (int)fxf;
        const float pz[4] = {1.0f, dz, dz * dz, dz * dz * dz};
        const float py[4] = {1.0f, dy, dy * dy, dy * dy * dy};
        pw4[tid][0] = make_float4(pz[0]*py[0], pz[0]*py[1], pz[0]*py[2], pz[0]*py[3]);
        pw4[tid][1] = make_float4(pz[1]*py[0], pz[1]*py[1], pz[1]*py[2], pz[1]*py[3]);
        pw4[tid][2] = make_float4(pz[2]*py[0], pz[2]*py[1], pz[2]*py[2], pz[2]*py[3]);
        pw4[tid][3] = make_float4(pz[3]*py[0], pz[3]*py[1], pz[3]*py[2], pz[3]*py[3]);
        pw4[tid][4] = make_float4(dx, dx * dx, dx * dx * dx, inten[n * ZPLANES + z]);
        pw4[tid][5] = make_float4(bg[n * ZPLANES + z], 0.f, 0.f, 0.f);
        const int match = (iz == z + 27) && (cy == 9) && (cx == 9);
        pint4[tid] = make_int4(iz, cy, cx, match);
    }

    // Slab base: cell (y,x) -> coefs[z+27][9+y][9+x][0..63]
    const float* slabBase = coefs + (((size_t)(z + 27) * SPL_H + 9) * SPL_W + 9) * 64;

    // ---- stage half A: rows 0..9 (cells 0..199) ----
    for (int g = tid; g < HALF_CHUNKS; g += 512) {
        const int row = g / 320;             // 320 chunks per row (20 cells * 16)
        const int rem = g - row * 320;
        slab4[g ^ ((g >> 4) & 15)] = ((const float4*)(slabBase + row * (SPL_W * 64)))[rem];
    }
    __syncthreads();

    float4 r[16];
    if (cell < HALF_CELLS) {
#pragma unroll
        for (int k = 0; k < 16; ++k)
            r[k] = slab4[cell * 16 + (k ^ (cell & 15))];
    }
    __syncthreads();   // half-A reads done before overwrite

    // ---- stage half B: rows 10..19 (cells 200..399) ----
    for (int g = tid; g < HALF_CHUNKS; g += 512) {
        const int row = g / 320;
        const int rem = g - row * 320;
        slab4[g ^ ((g >> 4) & 15)] = ((const float4*)(slabBase + (10 + row) * (SPL_W * 64)))[rem];
    }
    __syncthreads();

    if (cell >= HALF_CELLS && cell < NPIX) {
        const int L = cell - HALF_CELLS;
#pragma unroll
        for (int k = 0; k < 16; ++k)
            r[k] = slab4[L * 16 + (k ^ (L & 15))];
    }
    __syncthreads();   // half-B reads done before vals overwrite

    // ---- phase 2: emitter loop, vals into LDS (aliases slab4) ----
    float* vals = reinterpret_cast<float*>(slab4);   // E*400*4 = 12.8 KB <= 51.2 KB
    for (int e = 0; e < E; ++e) {
        const float4 wA = pw4[e][0], wB = pw4[e][1], wC = pw4[e][2], wD = pw4[e][3];
        const float4 dxv = pw4[e][4];
        const int4 pe = pint4[e];
        if (cell < NPIX) {
            float wq[16] = {wA.x, wA.y, wA.z, wA.w, wB.x, wB.y, wB.z, wB.w,
                            wC.x, wC.y, wC.z, wC.w, wD.x, wD.y, wD.z, wD.w};
            float v = 0.0f;
            if (pe.w) {
#pragma unroll
                for (int q = 0; q < 16; ++q) {
                    const float4 rq = r[q];
                    const float sx = fmaf(rq.w, dxv.z, fmaf(rq.z, dxv.y, fmaf(rq.y, dxv.x, rq.x)));
                    v = fmaf(wq[q], sx, v);
                }
            } else {
                // exact fallback (pos outside [0,1) lattice assumption): global gather
                const int y = cell / ROISIZE;
                const int x = cell - y * ROISIZE;
                int iy = y + pe.y; iy = min(max(iy, 0), SPL_H - 1);
                int ix = x + pe.z; ix = min(max(ix, 0), SPL_W - 1);
                const float4* cp = (const float4*)(coefs + (((size_t)pe.x * SPL_H + iy) * SPL_W + ix) * 64);
#pragma unroll
                for (int q = 0; q < 16; ++q) {
                    const float4 rq = cp[q];
                    const float sx = fmaf(rq.w, dxv.z, fmaf(rq.z, dxv.y, fmaf(rq.y, dxv.x, rq.x)));
                    v = fmaf(wq[q], sx, v);
                }
            }
            vals[e * NPIX + cell] = v;
        }
    }
    __syncthreads();

    // ---- phase 3: per-emitter totals (8 waves x 1 emitter) ----
    const int wid = tid >> 6;
    const int lane = tid & 63;
    {
        const int e = wid;               // E == 8 == number of waves
        float s = 0.0f;
        for (int c = lane; c < NPIX; c += 64) s += vals[e * NPIX + c];
#pragma unroll
        for (int off = 32; off > 0; off >>= 1) s += __shfl_down(s, off);
        if (lane == 0) {
            sscale[e] = pw4[e][4].w / s;   // I / total
            sbg[e] = pw4[e][5].x;
        }
    }
    __syncthreads();

    // ---- phase 4: scale + background + store ----
    if (cell < NPIX) {
        for (int e = 0; e < E; ++e) {
            const size_t n = (size_t)(group * E + e);
            out[(n * ZPLANES + z) * NPIX + cell] = fmaf(vals[e * NPIX + cell], sscale[e], sbg[e]);
        }
    }
}

extern "C" void kernel_launch(void* const* d_in, const int* in_sizes, int n_in,
                              void* d_out, int out_size, void* d_ws, size_t ws_size,
                              hipStream_t stream) {
    const float* pos   = (const float*)d_in[0];   // [512, 3]
    const float* inten = (const float*)d_in[1];   // [512, 8]
    const float* bg    = (const float*)d_in[2];   // [512, 8]
    const float* coefs = (const float*)d_in[3];   // [64, 40, 40, 64]
    float* out = (float*)d_out;                   // [512, 8, 20, 20]

    psf_kernel<<<ZPLANES * NGROUPS, 512, 0, stream>>>(pos, inten, bg, coefs, out);
}